// Round 1
// baseline (601.619 us; speedup 1.0000x reference)
//
#include <hip/hip_runtime.h>
#include <stdint.h>

// ---------------- common helpers ----------------

using f32x4 = __attribute__((ext_vector_type(4))) float;
using s16x8 = __attribute__((ext_vector_type(8))) short;

__device__ __forceinline__ ushort f2b(float f) {
    union { float f; uint32_t u; } v; v.f = f;
    uint32_t u = v.u;
    return (ushort)((u + 0x7fffu + ((u >> 16) & 1u)) >> 16);
}
__device__ __forceinline__ float b2f(ushort b) {
    union { uint32_t u; float f; } v; v.u = ((uint32_t)b) << 16;
    return v.f;
}
__device__ __forceinline__ float to_f(float f) { return f; }
__device__ __forceinline__ float to_f(ushort b) { return b2f(b); }

// async global->LDS, 16B per lane; LDS dest = wave-uniform base + lane*16
__device__ __forceinline__ void async_ld16(const ushort* g, ushort* l) {
    __builtin_amdgcn_global_load_lds(
        (const __attribute__((address_space(1))) void*)g,
        (__attribute__((address_space(3))) void*)l,
        16, 0, 0);
}

// s_waitcnt immediates (gfx9): vmcnt[3:0]|[15:14], expcnt[6:4], lgkmcnt[11:8]
#define WAITCNT_VM6   0x0F76  // vmcnt=6, lgkm/exp no-wait
#define WAITCNT_VM0   0x0F70  // vmcnt=0
#define WAITCNT_LGKM0 0xC07F  // lgkmcnt=0, vmcnt/exp no-wait

// ---------------- cast fp32 -> bf16 (vectorized x4) ----------------

__global__ __launch_bounds__(256) void cast_f2b4(const float* __restrict__ src,
                                                 ushort* __restrict__ dst,
                                                 long long n4) {
    long long i = (long long)blockIdx.x * 256 + threadIdx.x;
    if (i >= n4) return;
    float4 f = ((const float4*)src)[i];
    ushort4 o;
    o.x = f2b(f.x); o.y = f2b(f.y); o.z = f2b(f.z); o.w = f2b(f.w);
    ((ushort4*)dst)[i] = o;
}

// ---------------- bias concat: [bq|bk|bv] -> dst (3*1024 floats) ----------------

__global__ __launch_bounds__(256) void concat3(const float* __restrict__ a,
                                               const float* __restrict__ b,
                                               const float* __restrict__ c,
                                               float* __restrict__ dst) {
    int i = blockIdx.x * 256 + threadIdx.x;  // grid 12 blocks = 3072
    const float* s = (i < 1024) ? a : (i < 2048) ? b : c;
    dst[i] = s[i & 1023];
}

// ---------------- split-K partial reduce + cast to bf16 --------------------------

__global__ __launch_bounds__(256) void add2_cast(const float* __restrict__ a,
                                                 const float* __restrict__ b,
                                                 ushort* __restrict__ o,
                                                 long long n4) {
    long long i = (long long)blockIdx.x * 256 + threadIdx.x;
    if (i >= n4) return;
    float4 x = ((const float4*)a)[i];
    float4 y = ((const float4*)b)[i];
    ushort4 u;
    u.x = f2b(x.x + y.x); u.y = f2b(x.y + y.y);
    u.z = f2b(x.z + y.z); u.w = f2b(x.w + y.w);
    ((ushort4*)o)[i] = u;
}

// ---------------- transpose (fp32 or bf16 in) -> bf16 out ----------------
// src: [R][C] with row stride srcLd, dst: [C][R] row-major.
// Grid: (C/32, R/32, batch), block (32,8).

template <typename T>
__global__ __launch_bounds__(256) void transpose_to_bf16(const T* __restrict__ src,
                                                         ushort* __restrict__ dst,
                                                         int R, int C, int srcLd,
                                                         long long ss, long long ds) {
    __shared__ float tile[32][33];
    src += (long long)blockIdx.z * ss;
    dst += (long long)blockIdx.z * ds;
    const int c0 = blockIdx.x * 32;
    const int r0 = blockIdx.y * 32;
    const int tx = threadIdx.x, ty = threadIdx.y;
#pragma unroll
    for (int i = 0; i < 4; i++) {
        int r = r0 + ty + i * 8;
        tile[ty + i * 8][tx] = to_f(src[(long long)r * srcLd + c0 + tx]);
    }
    __syncthreads();
#pragma unroll
    for (int i = 0; i < 4; i++) {
        int r = c0 + ty + i * 8;  // row of dst, in [0, C)
        dst[(long long)r * R + r0 + tx] = f2b(tile[tx][ty + i * 8]);
    }
}

// ---- fused 4x (1024x1024) transpose-cast: z selects {wq,wk,wv,wo}, dst contiguous ----

__global__ __launch_bounds__(256) void transpose4_to_bf16(const float* __restrict__ s0,
                                                          const float* __restrict__ s1,
                                                          const float* __restrict__ s2,
                                                          const float* __restrict__ s3,
                                                          ushort* __restrict__ dst) {
    __shared__ float tile[32][33];
    const int D = 1024;
    const int z = blockIdx.z;
    const float* src = (z == 0) ? s0 : (z == 1) ? s1 : (z == 2) ? s2 : s3;
    dst += (long long)z * D * D;
    const int c0 = blockIdx.x * 32;
    const int r0 = blockIdx.y * 32;
    const int tx = threadIdx.x, ty = threadIdx.y;
#pragma unroll
    for (int i = 0; i < 4; i++) {
        int r = r0 + ty + i * 8;
        tile[ty + i * 8][tx] = src[(long long)r * D + c0 + tx];
    }
    __syncthreads();
#pragma unroll
    for (int i = 0; i < 4; i++) {
        int r = c0 + ty + i * 8;
        dst[(long long)r * D + r0 + tx] = f2b(tile[tx][ty + i * 8]);
    }
}

// ---------------- bf16 MFMA GEMM, 256x256 8-phase (m201-template port) -----------
// C[M,N] = A[M,K] * BT[N,K]^T (+bias, relu, scale). 512 threads = 8 waves (2M x 4N),
// per-wave 128x64 output = acc[8][4] f32x4. BK=64; LDS = 2buf x (A 32KB + B 32KB)
// = 128 KB -> 1 block/CU, 8 waves (the HK/m201 operating point).
//
// Staged as 4 half-tiles/K-tile ([128 rows][64 cols] bf16 each, 2 global_load_lds
// per thread per half-tile). T2 swizzle: 16B slot s at row r holds logical slot
// s^(r&7); applied on the global SOURCE address (LDS dest stays linear, m104) and
// on the ds_read address (both-sides-or-neither, rule #21) -> conflict-free b128.
//
// Phases per K-tile t (buf p), 2 barriers each; reads distributed (16,8,0,0) so
// LDS regions free early enough for 3-half-tile-deep prefetch:
//   Ph1: read a0(8)+b_all(8); stage A1(t+1)->p^1;          MFMA Q00 acc[0..3][0..1]
//   Ph2: read a1(8);          stage B0(t+2)->p  (B free@Ph1end); Q01 acc[0..3][2..3]
//   Ph3:                      stage A0(t+2)->p  (A free@Ph2end); Q10 acc[4..7][0..1]
//   Ph4:                      stage B1(t+2)->p  (B free@Ph1end); Q11 acc[4..7][2..3]
//        then vmcnt(6) (drains exactly tile t+1's 8 loads; 3 half-tiles stay in
//        flight — never vmcnt(0) in steady state, T4), barrier.
// Prologue: tile0 {B0,A0,B1,A1}->buf0 + tile1 {B0,A0,B1}->buf1, vmcnt(6), barrier.
// Tail: at t=kTiles-2 vmcnt(0) (all stages beyond are guarded out -> nothing in
// flight at endpgm). setprio(1) around each MFMA cluster (T5). XCD panel swizzle
// kept (gridDim.y must be a multiple of 8).
// Split-K (kChunks>1): chunk kIdx writes partials at C + kIdx*sK (plain stores);
// bias on chunk 0 only; reduction fused downstream (residual_ln / add2_cast).

template <int OUT_BF16, int RELU, int HAS_BIAS>
__global__ __launch_bounds__(512, 2) void gemm256(const ushort* __restrict__ A,
                                                  const ushort* __restrict__ BT,
                                                  void* __restrict__ Cp,
                                                  const float* __restrict__ bias,
                                                  int K, int kChunks, float scale,
                                                  int lda, int ldb, int ldc,
                                                  long long sA, long long sB,
                                                  long long sC, long long sK) {
    __shared__ ushort Asl[32768];  // [2 buf][2 half][128][64] = 64 KB
    __shared__ ushort Bsl[32768];  // 64 KB

    const int tid = threadIdx.x;
    const int kIdx = blockIdx.z % kChunks;
    const int bz = blockIdx.z / kChunks;
    const int kLen = K / kChunks;
    const int kOff = kIdx * kLen;
    const int kTiles = kLen >> 6;
    const ushort* Ab = A + (long long)bz * sA;
    const ushort* Bb = BT + (long long)bz * sB;

    // XCD-panel swizzle (T1; bijective since W*H % 8 == 0 for all our grids)
    const int W = gridDim.x, H = gridDim.y;
    const int bidx = blockIdx.y * W + blockIdx.x;
    const int Hp = H >> 3;
    const int xcd = bidx & 7;
    const int sb = bidx >> 3;
    const int tn = sb / Hp;
    const int tm = xcd * Hp + sb % Hp;

    const int lane = tid & 63;
    const int w = tid >> 6;    // wave 0..7
    const int wm = w >> 2;     // M half 0..1
    const int wn = w & 3;      // N quarter 0..3
    const int l16 = lane & 15;
    const int quad = lane >> 4;

    // ---- staging geometry: per (wave,instr) 1KB linear LDS block = 8 rows x 64 cols.
    // physical slot (lane&7) must receive logical slot (lane&7)^(row&7); row&7 = lane>>3.
    const int lr = lane >> 3;
    const int swslot = (lane & 7) ^ lr;
    const ushort* AgS = Ab + (long long)(tm * 256 + w * 16 + lr) * lda + kOff + swslot * 8;
    const ushort* BgS = Bb + (long long)(tn * 256 + w * 16 + lr) * ldb + kOff + swslot * 8;
    ushort* AsW = Asl + w * 1024;
    ushort* BsW = Bsl + w * 1024;

#define STG_A(h, tt, bf) { const ushort* g_ = AgS + (h) * 128 * lda + (tt) * 64;   \
        ushort* d_ = AsW + (bf) * 16384 + (h) * 8192;                              \
        async_ld16(g_, d_); async_ld16(g_ + 8 * lda, d_ + 512); }
#define STG_B(h, tt, bf) { const ushort* g_ = BgS + (h) * 128 * ldb + (tt) * 64;   \
        ushort* d_ = BsW + (bf) * 16384 + (h) * 8192;                              \
        async_ld16(g_, d_); async_ld16(g_ + 8 * ldb, d_ + 512); }

    // ---- fragment ds_read offsets (elements); row&7 == l16&7 for all fragments,
    // so the XOR term is a per-lane constant.
    const int csw0 = (quad * 8) ^ ((l16 & 7) * 8);        // ks=0
    const int csw1 = (32 + quad * 8) ^ ((l16 & 7) * 8);   // ks=1
    const int aoff0 = l16 * 64 + csw0;
    const int aoff1 = l16 * 64 + csw1;
    const ushort* AhB = Asl + wm * 8192;                       // + p*16384 (+4096 for a1)
    const ushort* BhB = Bsl + (wn >> 1) * 8192 + (wn & 1) * 4096;  // + p*16384

    f32x4 acc[8][4];
#pragma unroll
    for (int i = 0; i < 8; i++)
#pragma unroll
        for (int j = 0; j < 4; j++) acc[i][j] = (f32x4){0.f, 0.f, 0.f, 0.f};

    // ---- prologue: tile0 full -> buf0; tile1 {B0,A0,B1} -> buf1; drain tile0.
    STG_B(0, 0, 0); STG_A(0, 0, 0); STG_B(1, 0, 0); STG_A(1, 0, 0);
    STG_B(0, 1, 1); STG_A(0, 1, 1); STG_B(1, 1, 1);
    __builtin_amdgcn_s_waitcnt(WAITCNT_VM6);
    __builtin_amdgcn_s_barrier();

    int p = 0;
    for (int t = 0; t < kTiles; ++t, p ^= 1) {
        const ushort* Ap = AhB + p * 16384;
        const ushort* Bp = BhB + p * 16384;
        s16x8 a0[4][2], a1[4][2], bb[4][2];

        // ---- phase 1: a0 + all b; stage A1(t+1); Q00
#pragma unroll
        for (int i = 0; i < 4; i++) {
            a0[i][0] = *(const s16x8*)(Ap + i * 1024 + aoff0);
            a0[i][1] = *(const s16x8*)(Ap + i * 1024 + aoff1);
        }
#pragma unroll
        for (int j = 0; j < 4; j++) {
            bb[j][0] = *(const s16x8*)(Bp + j * 1024 + aoff0);
            bb[j][1] = *(const s16x8*)(Bp + j * 1024 + aoff1);
        }
        if (t + 1 < kTiles) STG_A(1, t + 1, p ^ 1);
        __builtin_amdgcn_s_barrier();
        __builtin_amdgcn_s_waitcnt(WAITCNT_LGKM0);
        __builtin_amdgcn_s_setprio(1);
#pragma unroll
        for (int ks = 0; ks < 2; ks++)
#pragma unroll
            for (int i = 0; i < 4; i++)
#pragma unroll
                for (int j = 0; j < 2; j++)
                    acc[i][j] = __builtin_amdgcn_mfma_f32_16x16x32_bf16(
                        a0[i][ks], bb[j][ks], acc[i][j], 0, 0, 0);
        __builtin_amdgcn_s_setprio(0);
        __builtin_amdgcn_s_barrier();

        // ---- phase 2: a1; stage B0(t+2) (B-halves freed at Ph1-end); Q01
#pragma unroll
        for (int i = 0; i < 4; i++) {
            a1[i][0] = *(const s16x8*)(Ap + 4096 + i * 1024 + aoff0);
            a1[i][1] = *(const s16x8*)(Ap + 4096 + i * 1024 + aoff1);
        }
        if (t + 2 < kTiles) STG_B(0, t + 2, p);
        __builtin_amdgcn_s_barrier();
        __builtin_amdgcn_s_setprio(1);
#pragma unroll
        for (int ks = 0; ks < 2; ks++)
#pragma unroll
            for (int i = 0; i < 4; i++)
#pragma unroll
                for (int j = 0; j < 2; j++)
                    acc[i][2 + j] = __builtin_amdgcn_mfma_f32_16x16x32_bf16(
                        a0[i][ks], bb[2 + j][ks], acc[i][2 + j], 0, 0, 0);
        __builtin_amdgcn_s_setprio(0);
        __builtin_amdgcn_s_barrier();

        // ---- phase 3: stage A0(t+2) (A-halves freed at Ph2-end); Q10
        if (t + 2 < kTiles) STG_A(0, t + 2, p);
        __builtin_amdgcn_s_barrier();
        __builtin_amdgcn_s_waitcnt(WAITCNT_LGKM0);
        __builtin_amdgcn_s_setprio(1);
#pragma unroll
        for (int ks = 0; ks < 2; ks++)
#pragma unroll
            for (int i = 0; i < 4; i++)
#pragma unroll
                for (int j = 0; j < 2; j++)
                    acc[4 + i][j] = __builtin_amdgcn_mfma_f32_16x16x32_bf16(
                        a1[i][ks], bb[j][ks], acc[4 + i][j], 0, 0, 0);
        __builtin_amdgcn_s_setprio(0);
        __builtin_amdgcn_s_barrier();

        // ---- phase 4: stage B1(t+2); Q11; counted vmcnt drains exactly tile t+1
        if (t + 2 < kTiles) STG_B(1, t + 2, p);
        __builtin_amdgcn_s_barrier();
        __builtin_amdgcn_s_setprio(1);
#pragma unroll
        for (int ks = 0; ks < 2; ks++)
#pragma unroll
            for (int i = 0; i < 4; i++)
#pragma unroll
                for (int j = 0; j < 2; j++)
                    acc[4 + i][2 + j] = __builtin_amdgcn_mfma_f32_16x16x32_bf16(
                        a1[i][ks], bb[2 + j][ks], acc[4 + i][2 + j], 0, 0, 0);
        __builtin_amdgcn_s_setprio(0);
        if (t + 2 < kTiles) __builtin_amdgcn_s_waitcnt(WAITCNT_VM6);
        else if (t + 1 < kTiles) __builtin_amdgcn_s_waitcnt(WAITCNT_VM0);
        __builtin_amdgcn_s_barrier();
    }
#undef STG_A
#undef STG_B

    // ---- epilogue: C/D layout col = lane&15, row = quad*4 + reg [m89/m91]
    const long long cb = (long long)bz * sC + (long long)kIdx * sK;
    float* Cf = (float*)Cp;
    ushort* Cb = (ushort*)Cp;
#pragma unroll
    for (int j = 0; j < 4; j++) {
        const int col = tn * 256 + wn * 64 + j * 16 + l16;
        float bv = (HAS_BIAS && kIdx == 0) ? bias[col] : 0.0f;
#pragma unroll
        for (int i = 0; i < 8; i++) {
            const int row0 = tm * 256 + wm * 128 + i * 16 + quad * 4;
#pragma unroll
            for (int r = 0; r < 4; r++) {
                float v = acc[i][j][r] * scale + bv;
                if (RELU) v = v > 0.f ? v : 0.f;
                long long idx = cb + (long long)(row0 + r) * ldc + col;
                if (OUT_BF16) Cb[idx] = f2b(v);
                else Cf[idx] = v;
            }
        }
    }
}

// ---------------- row softmax: bf16 [rows][2048] -> bf16, vectorized 8/thread -------

__global__ __launch_bounds__(256) void softmax_rows(const ushort* __restrict__ S,
                                                    ushort* __restrict__ P) {
    const int C = 2048;
    const long long row = blockIdx.x;
    const int tid = threadIdx.x;
    const ushort4* s4 = (const ushort4*)(S + row * C) + tid * 2;  // 8 contiguous elems
    ushort4 a = s4[0], bq = s4[1];
    float v[8];
    v[0] = b2f(a.x); v[1] = b2f(a.y); v[2] = b2f(a.z); v[3] = b2f(a.w);
    v[4] = b2f(bq.x); v[5] = b2f(bq.y); v[6] = b2f(bq.z); v[7] = b2f(bq.w);
    float mx = -1e30f;
#pragma unroll
    for (int i = 0; i < 8; i++) mx = fmaxf(mx, v[i]);
    __shared__ float red[256];
    red[tid] = mx;
    __syncthreads();
    for (int off = 128; off > 0; off >>= 1) {
        if (tid < off) red[tid] = fmaxf(red[tid], red[tid + off]);
        __syncthreads();
    }
    mx = red[0];
    __syncthreads();
    float sum = 0.f;
#pragma unroll
    for (int i = 0; i < 8; i++) {
        v[i] = __expf(v[i] - mx);
        sum += v[i];
    }
    red[tid] = sum;
    __syncthreads();
    for (int off = 128; off > 0; off >>= 1) {
        if (tid < off) red[tid] += red[tid + off];
        __syncthreads();
    }
    float inv = 1.f / red[0];
    ushort4 o0, o1;
    o0.x = f2b(v[0] * inv); o0.y = f2b(v[1] * inv); o0.z = f2b(v[2] * inv); o0.w = f2b(v[3] * inv);
    o1.x = f2b(v[4] * inv); o1.y = f2b(v[5] * inv); o1.z = f2b(v[6] * inv); o1.w = f2b(v[7] * inv);
    ushort4* p4 = (ushort4*)(P + row * C) + tid * 2;
    p4[0] = o0;
    p4[1] = o1;
}

// ---------------- fused residual(+partial-sum) + LayerNorm (D=1024) ----------------
// out = LN(X + Y + (Y2?)) ; Y2 nullable (split-K partial reduction fused here).

__global__ __launch_bounds__(256) void residual_ln(const float* __restrict__ X,
                                                   const float* __restrict__ Y,
                                                   const float* __restrict__ Y2,
                                                   const float* __restrict__ g,
                                                   const float* __restrict__ be,
                                                   float* __restrict__ outf,
                                                   ushort* __restrict__ outb) {
    const int D = 1024;
    const long long row = blockIdx.x;
    const float* x = X + row * D;
    const float* y = Y + row * D;
    const float* y2 = Y2 ? Y2 + row * D : nullptr;
    const int tid = threadIdx.x;
    float v[4];
    float s = 0.f, s2 = 0.f;
#pragma unroll
    for (int i = 0; i < 4; i++) {
        int c = tid + i * 256;
        float t = x[c] + y[c];
        if (y2) t += y2[c];
        v[i] = t;
        s += t;
        s2 += t * t;
    }
    __shared__ float r1[256], r2[256];
    r1[tid] = s;
    r2[tid] = s2;
    __syncthreads();
    for (int off = 128; off > 0; off >>= 1) {
        if (tid < off) {
            r1[tid] += r1[tid + off];
            r2[tid] += r2[tid + off];
        }
        __syncthreads();
    }
    float mu = r1[0] * (1.f / 1024.f);
    float var = r2[0] * (1.f / 1024.f) - mu * mu;
    float inv = rsqrtf(var + 1e-5f);
    float* of = outf + row * D;
    ushort* ob = outb ? outb + row * D : nullptr;
#pragma unroll
    for (int i = 0; i < 4; i++) {
        int c = tid + i * 256;
        float o = (v[i] - mu) * inv * g[c] + be[c];
        of[c] = o;
        if (ob) ob[c] = f2b(o);
    }
}

// ---------------- launch ----------------

extern "C" void kernel_launch(void* const* d_in, const int* in_sizes, int n_in,
                              void* d_out, int out_size, void* d_ws, size_t ws_size,
                              hipStream_t stream) {
    const float* x  = (const float*)d_in[0];
    const float* wq = (const float*)d_in[1];
    const float* bq = (const float*)d_in[2];
    const float* wk = (const float*)d_in[3];
    const float* bk = (const float*)d_in[4];
    const float* wv = (const float*)d_in[5];
    const float* bv = (const float*)d_in[6];
    const float* wo = (const float*)d_in[7];
    const float* bo = (const float*)d_in[8];
    const float* w1 = (const float*)d_in[9];
    const float* b1 = (const float*)d_in[10];
    const float* w2 = (const float*)d_in[11];
    const float* b2 = (const float*)d_in[12];
    const float* g1 = (const float*)d_in[13];
    const float* be1 = (const float*)d_in[14];
    const float* g2 = (const float*)d_in[15];
    const float* be2 = (const float*)d_in[16];
    float* out = (float*)d_out;
    char* ws = (char*)d_ws;

    const int Bz = 4, S = 2048, D = 1024, F = 4096;
    const int T = Bz * S;  // 8192 rows
    const size_t MBy = 1024ull * 1024ull;

    // workspace layout (byte offsets), lifetime-based reuse; peak 201 MB
    ushort* qkvT = (ushort*)(ws + 0);        // 6 MB  [3072][1024]; woT follows contiguously
    ushort* woT  = (ushort*)(ws + 6 * MBy);  // 2 MB
    ushort* w1T  = (ushort*)(ws + 8 * MBy);  // 8 MB   [F][D]
    ushort* w2T  = (ushort*)(ws + 16 * MBy); // 8 MB   [D][F]
    float*  bqkv = (float*)(ws + 24 * MBy);  // 12 KB  (dead after QKV gemm)
    ushort* xb   = (ushort*)(ws + 25 * MBy); // 16 MB  (dead after QKV gemm)
    ushort* qkv  = (ushort*)(ws + 41 * MBy); // 48 MB  [T][3072] (dead after scores+vT)
    ushort* vT   = (ushort*)(ws + 89 * MBy); // 16 MB  [B][D][S] (dead after ctx)
    ushort* scb  = (ushort*)(ws + 105 * MBy); // 32 MB bf16 scores (dead after softmax)
    ushort* attn = (ushort*)(ws + 169 * MBy); // 32 MB (dead after ctx)
    // reuse (non-overlapping lifetimes):
    float*  ctx0 = (float*)(ws + 105 * MBy); // 32 MB over scb (dead after add2_cast)
    float*  ctx1 = (float*)(ws + 137 * MBy); // 32 MB (dead after add2_cast)
    ushort* ctxb = (ushort*)(ws + 25 * MBy); // 16 MB over xb (dead after wo)
    float*  ao0 = (float*)(ws + 105 * MBy);  // 32 MB over ctx0 (dead after ln1)
    float*  ao1 = (float*)(ws + 137 * MBy);  // 32 MB (dead after ln1)
    float*  x1  = (float*)(ws + 41 * MBy);   // 32 MB over qkv (live to ln2)
    ushort* x1b = (ushort*)(ws + 73 * MBy);  // 16 MB over qkv (dead after ffn1)
    ushort* h   = (ushort*)(ws + 105 * MBy); // 64 MB over ao (after ln1)
    float*  ff0 = (float*)(ws + 169 * MBy);  // 32 MB over attn
    float*  ff1 = (float*)(ws + 73 * MBy);   // 32 MB over x1b+vT (both dead by ffn2)

    dim3 b32(32, 8);

    // 1) cast x -> bf16
    cast_f2b4<<<(T * D) / 1024, 256, 0, stream>>>(x, xb, (long long)(T * D) / 4);

    // 2) transpose-cast weights: wq/wk/wv/wo -> [qkvT|woT] in ONE dispatch; w1, w2
    transpose4_to_bf16<<<dim3(32, 32, 4), b32, 0, stream>>>(wq, wk, wv, wo, qkvT);
    transpose_to_bf16<float><<<dim3(128, 32, 1), b32, 0, stream>>>(w1, w1T, D, F, F, 0, 0);
    transpose_to_bf16<float><<<dim3(32, 128, 1), b32, 0, stream>>>(w2, w2T, F, D, D, 0, 0);

    // 3) fused bias vector [bq|bk|bv]
    concat3<<<12, 256, 0, stream>>>(bq, bk, bv, bqkv);

    // 4) fused QKV projection: [T][1024] x [3072][1024]^T -> [T][3072] bf16 (384 blocks)
    gemm256<1, 0, 1><<<dim3(3 * D / 256, T / 256, 1), 512, 0, stream>>>(
        xb, qkvT, qkv, bqkv, D, 1, 1.f, D, D, 3 * D, 0, 0, 0, 0);

    // 5) V^T per batch: qkv v-slice [S][1024] (ld 3072) -> [D][S]
    transpose_to_bf16<ushort><<<dim3(D / 32, S / 32, Bz), b32, 0, stream>>>(
        qkv + 2048, vT, S, D, 3 * D, (long long)S * 3 * D, (long long)S * D);

    // 6) scores = Q K^T / 32 -> bf16; A=q, B=k slices of qkv (ld 3072) (256 blocks)
    gemm256<1, 0, 0><<<dim3(S / 256, S / 256, Bz), 512, 0, stream>>>(
        qkv, qkv + 1024, scb, nullptr, D, 1, 0.03125f, 3 * D, 3 * D, S,
        (long long)S * 3 * D, (long long)S * 3 * D, (long long)S * S, 0);

    // 7) softmax rows -> bf16 attn
    softmax_rows<<<T, 256, 0, stream>>>(scb, attn);

    // 8) ctx partials = attn @ V (BT = V^T [D][S]), split-K=2 -> fp32 (256 blocks)
    gemm256<0, 0, 0><<<dim3(D / 256, S / 256, Bz * 2), 512, 0, stream>>>(
        attn, vT, ctx0, nullptr, S, 2, 1.f, S, S, D,
        (long long)S * S, (long long)D * S, (long long)S * D, (long long)(ctx1 - ctx0));

    // 8b) ctx = ctx0 + ctx1 -> bf16
    add2_cast<<<(T * D) / 1024, 256, 0, stream>>>(ctx0, ctx1, ctxb, (long long)(T * D) / 4);

    // 9) attn_out partials = ctx @ wo^T (+bo chunk 0), split-K=2 (256 blocks)
    gemm256<0, 0, 1><<<dim3(D / 256, T / 256, 2), 512, 0, stream>>>(
        ctxb, woT, ao0, bo, D, 2, 1.f, D, D, D, 0, 0, 0, (long long)(ao1 - ao0));

    // 10) x1 = LN(x + ao0 + ao1) -> fp32 + bf16 (split-K reduction fused)
    residual_ln<<<T, 256, 0, stream>>>(x, ao0, ao1, g1, be1, x1, x1b);

    // 11) h = relu(x1 @ w1 + b1) (bf16, 512 blocks)
    gemm256<1, 1, 1><<<dim3(F / 256, T / 256, 1), 512, 0, stream>>>(
        x1b, w1T, h, b1, D, 1, 1.f, D, D, F, 0, 0, 0, 0);

    // 12) ff partials = h @ w2 (+b2 on chunk 0), split-K=2 (256 blocks)
    gemm256<0, 0, 1><<<dim3(D / 256, T / 256, 2), 512, 0, stream>>>(
        h, w2T, ff0, b2, F, 2, 1.f, F, F, D, 0, 0, 0, (long long)(ff1 - ff0));

    // 13) out = LN(x1 + ff0 + ff1) -> d_out fp32 (split-K reduction fused)
    residual_ln<<<T, 256, 0, stream>>>(x1, ff0, ff1, g2, be2, out, nullptr);
}

// Round 2
// 565.066 us; speedup vs baseline: 1.0647x; 1.0647x over previous
//
#include <hip/hip_runtime.h>
#include <stdint.h>

// ---------------- common helpers ----------------

using f32x4 = __attribute__((ext_vector_type(4))) float;
using s16x8 = __attribute__((ext_vector_type(8))) short;

__device__ __forceinline__ ushort f2b(float f) {
    union { float f; uint32_t u; } v; v.f = f;
    uint32_t u = v.u;
    return (ushort)((u + 0x7fffu + ((u >> 16) & 1u)) >> 16);
}
__device__ __forceinline__ float b2f(ushort b) {
    union { uint32_t u; float f; } v; v.u = ((uint32_t)b) << 16;
    return v.f;
}
__device__ __forceinline__ float to_f(float f) { return f; }
__device__ __forceinline__ float to_f(ushort b) { return b2f(b); }

// async global->LDS, 16B per lane; LDS dest = wave-uniform base + lane*16
__device__ __forceinline__ void async_ld16(const ushort* g, ushort* l) {
    __builtin_amdgcn_global_load_lds(
        (const __attribute__((address_space(1))) void*)g,
        (__attribute__((address_space(3))) void*)l,
        16, 0, 0);
}

// s_waitcnt immediates (gfx9): vmcnt[3:0]|[15:14], expcnt[6:4], lgkmcnt[11:8]
#define WAITCNT_VM6   0x0F76  // vmcnt=6, lgkm/exp no-wait
#define WAITCNT_VM0   0x0F70  // vmcnt=0
#define WAITCNT_LGKM0 0xC07F  // lgkmcnt=0, vmcnt/exp no-wait

// ---------------- cast fp32 -> bf16 (vectorized x4) ----------------

__global__ __launch_bounds__(256) void cast_f2b4(const float* __restrict__ src,
                                                 ushort* __restrict__ dst,
                                                 long long n4) {
    long long i = (long long)blockIdx.x * 256 + threadIdx.x;
    if (i >= n4) return;
    float4 f = ((const float4*)src)[i];
    ushort4 o;
    o.x = f2b(f.x); o.y = f2b(f.y); o.z = f2b(f.z); o.w = f2b(f.w);
    ((ushort4*)dst)[i] = o;
}

// ---------------- bias concat: [bq|bk|bv] -> dst (3*1024 floats) ----------------

__global__ __launch_bounds__(256) void concat3(const float* __restrict__ a,
                                               const float* __restrict__ b,
                                               const float* __restrict__ c,
                                               float* __restrict__ dst) {
    int i = blockIdx.x * 256 + threadIdx.x;  // grid 12 blocks = 3072
    const float* s = (i < 1024) ? a : (i < 2048) ? b : c;
    dst[i] = s[i & 1023];
}

// ---------------- split-K partial reduce + cast to bf16 --------------------------

__global__ __launch_bounds__(256) void add2_cast(const float* __restrict__ a,
                                                 const float* __restrict__ b,
                                                 ushort* __restrict__ o,
                                                 long long n4) {
    long long i = (long long)blockIdx.x * 256 + threadIdx.x;
    if (i >= n4) return;
    float4 x = ((const float4*)a)[i];
    float4 y = ((const float4*)b)[i];
    ushort4 u;
    u.x = f2b(x.x + y.x); u.y = f2b(x.y + y.y);
    u.z = f2b(x.z + y.z); u.w = f2b(x.w + y.w);
    ((ushort4*)o)[i] = u;
}

// ---------------- transpose (fp32 or bf16 in) -> bf16 out ----------------
// src: [R][C] with row stride srcLd, dst: [C][R] row-major.
// Grid: (C/32, R/32, batch), block (32,8).

template <typename T>
__global__ __launch_bounds__(256) void transpose_to_bf16(const T* __restrict__ src,
                                                         ushort* __restrict__ dst,
                                                         int R, int C, int srcLd,
                                                         long long ss, long long ds) {
    __shared__ float tile[32][33];
    src += (long long)blockIdx.z * ss;
    dst += (long long)blockIdx.z * ds;
    const int c0 = blockIdx.x * 32;
    const int r0 = blockIdx.y * 32;
    const int tx = threadIdx.x, ty = threadIdx.y;
#pragma unroll
    for (int i = 0; i < 4; i++) {
        int r = r0 + ty + i * 8;
        tile[ty + i * 8][tx] = to_f(src[(long long)r * srcLd + c0 + tx]);
    }
    __syncthreads();
#pragma unroll
    for (int i = 0; i < 4; i++) {
        int r = c0 + ty + i * 8;  // row of dst, in [0, C)
        dst[(long long)r * R + r0 + tx] = f2b(tile[tx][ty + i * 8]);
    }
}

// ---- fused 4x (1024x1024) transpose-cast: z selects {wq,wk,wv,wo}, dst contiguous ----

__global__ __launch_bounds__(256) void transpose4_to_bf16(const float* __restrict__ s0,
                                                          const float* __restrict__ s1,
                                                          const float* __restrict__ s2,
                                                          const float* __restrict__ s3,
                                                          ushort* __restrict__ dst) {
    __shared__ float tile[32][33];
    const int D = 1024;
    const int z = blockIdx.z;
    const float* src = (z == 0) ? s0 : (z == 1) ? s1 : (z == 2) ? s2 : s3;
    dst += (long long)z * D * D;
    const int c0 = blockIdx.x * 32;
    const int r0 = blockIdx.y * 32;
    const int tx = threadIdx.x, ty = threadIdx.y;
#pragma unroll
    for (int i = 0; i < 4; i++) {
        int r = r0 + ty + i * 8;
        tile[ty + i * 8][tx] = src[(long long)r * D + c0 + tx];
    }
    __syncthreads();
#pragma unroll
    for (int i = 0; i < 4; i++) {
        int r = c0 + ty + i * 8;
        dst[(long long)r * D + r0 + tx] = f2b(tile[tx][ty + i * 8]);
    }
}

// ---------------- bf16 MFMA GEMM, 256x256 8-phase (m201-template port) -----------
// C[M,N] = A[M,K] * BT[N,K]^T (+bias, relu, scale). 512 threads = 8 waves (2M x 4N),
// per-wave 128x64 output = acc[8][4] f32x4. BK=64; LDS = 2buf x (A 32KB + B 32KB)
// = 128 KB -> 1 block/CU, 8 waves. K-loop unchanged from R1 (race-screened;
// SQ_LDS_BANK_CONFLICT == 0 verified).
//
// R2 change: LDS-staged COALESCED epilogue. R1 counters: WRITE_SIZE 152 MB for a
// 64 MB logical output (2.4x partial-line write amplification; 32B segments across
// 4 rows per store). Now: after the K-loop the 128 KB LDS is dead -> stage the
// C-tile in LDS (group-XOR swizzle g ^= (row>>2)&3 == quad: 4 quads -> 4 distinct
// bank octets, conflict-free ds_write; readout is full-row -> conflict-free), then
// store full contiguous rows: bf16 = 512B/row per half-wave, fp32 = 1024B/row per
// wave, two 128-row half-passes (256x256 f32 > LDS).
// Split-K (kChunks>1): chunk kIdx writes partials at C + kIdx*sK (plain stores);
// bias on chunk 0 only; reduction fused downstream (residual_ln / add2_cast).

template <int OUT_BF16, int RELU, int HAS_BIAS>
__global__ __launch_bounds__(512, 2) void gemm256(const ushort* __restrict__ A,
                                                  const ushort* __restrict__ BT,
                                                  void* __restrict__ Cp,
                                                  const float* __restrict__ bias,
                                                  int K, int kChunks, float scale,
                                                  int lda, int ldb, int ldc,
                                                  long long sA, long long sB,
                                                  long long sC, long long sK) {
    __shared__ ushort SH[65536];   // 128 KB: K-loop [A 64KB | B 64KB]; epilogue C-stage
    ushort* Asl = SH;
    ushort* Bsl = SH + 32768;

    const int tid = threadIdx.x;
    const int kIdx = blockIdx.z % kChunks;
    const int bz = blockIdx.z / kChunks;
    const int kLen = K / kChunks;
    const int kOff = kIdx * kLen;
    const int kTiles = kLen >> 6;
    const ushort* Ab = A + (long long)bz * sA;
    const ushort* Bb = BT + (long long)bz * sB;

    // XCD-panel swizzle (T1; bijective since gridDim.y % 8 == 0 for all our grids)
    const int W = gridDim.x, H = gridDim.y;
    const int bidx = blockIdx.y * W + blockIdx.x;
    const int Hp = H >> 3;
    const int xcd = bidx & 7;
    const int sb = bidx >> 3;
    const int tn = sb / Hp;
    const int tm = xcd * Hp + sb % Hp;

    const int lane = tid & 63;
    const int w = tid >> 6;    // wave 0..7
    const int wm = w >> 2;     // M half 0..1
    const int wn = w & 3;      // N quarter 0..3
    const int l16 = lane & 15;
    const int quad = lane >> 4;

    // ---- staging geometry: per (wave,instr) 1KB linear LDS block = 8 rows x 64 cols.
    // physical slot (lane&7) must receive logical slot (lane&7)^(row&7); row&7 = lane>>3.
    const int lr = lane >> 3;
    const int swslot = (lane & 7) ^ lr;
    const ushort* AgS = Ab + (long long)(tm * 256 + w * 16 + lr) * lda + kOff + swslot * 8;
    const ushort* BgS = Bb + (long long)(tn * 256 + w * 16 + lr) * ldb + kOff + swslot * 8;
    ushort* AsW = Asl + w * 1024;
    ushort* BsW = Bsl + w * 1024;

#define STG_A(h, tt, bf) { const ushort* g_ = AgS + (h) * 128 * lda + (tt) * 64;   \
        ushort* d_ = AsW + (bf) * 16384 + (h) * 8192;                              \
        async_ld16(g_, d_); async_ld16(g_ + 8 * lda, d_ + 512); }
#define STG_B(h, tt, bf) { const ushort* g_ = BgS + (h) * 128 * ldb + (tt) * 64;   \
        ushort* d_ = BsW + (bf) * 16384 + (h) * 8192;                              \
        async_ld16(g_, d_); async_ld16(g_ + 8 * ldb, d_ + 512); }

    // ---- fragment ds_read offsets (elements); row&7 == l16&7 for all fragments,
    // so the XOR term is a per-lane constant.
    const int csw0 = (quad * 8) ^ ((l16 & 7) * 8);        // ks=0
    const int csw1 = (32 + quad * 8) ^ ((l16 & 7) * 8);   // ks=1
    const int aoff0 = l16 * 64 + csw0;
    const int aoff1 = l16 * 64 + csw1;
    const ushort* AhB = Asl + wm * 8192;                       // + p*16384 (+4096 for a1)
    const ushort* BhB = Bsl + (wn >> 1) * 8192 + (wn & 1) * 4096;  // + p*16384

    f32x4 acc[8][4];
#pragma unroll
    for (int i = 0; i < 8; i++)
#pragma unroll
        for (int j = 0; j < 4; j++) acc[i][j] = (f32x4){0.f, 0.f, 0.f, 0.f};

    // ---- prologue: tile0 full -> buf0; tile1 {B0,A0,B1} -> buf1; drain tile0.
    STG_B(0, 0, 0); STG_A(0, 0, 0); STG_B(1, 0, 0); STG_A(1, 0, 0);
    STG_B(0, 1, 1); STG_A(0, 1, 1); STG_B(1, 1, 1);
    __builtin_amdgcn_s_waitcnt(WAITCNT_VM6);
    __builtin_amdgcn_s_barrier();

    int p = 0;
    for (int t = 0; t < kTiles; ++t, p ^= 1) {
        const ushort* Ap = AhB + p * 16384;
        const ushort* Bp = BhB + p * 16384;
        s16x8 a0[4][2], a1[4][2], bb[4][2];

        // ---- phase 1: a0 + all b; stage A1(t+1); Q00
#pragma unroll
        for (int i = 0; i < 4; i++) {
            a0[i][0] = *(const s16x8*)(Ap + i * 1024 + aoff0);
            a0[i][1] = *(const s16x8*)(Ap + i * 1024 + aoff1);
        }
#pragma unroll
        for (int j = 0; j < 4; j++) {
            bb[j][0] = *(const s16x8*)(Bp + j * 1024 + aoff0);
            bb[j][1] = *(const s16x8*)(Bp + j * 1024 + aoff1);
        }
        if (t + 1 < kTiles) STG_A(1, t + 1, p ^ 1);
        __builtin_amdgcn_s_barrier();
        __builtin_amdgcn_s_waitcnt(WAITCNT_LGKM0);
        __builtin_amdgcn_s_setprio(1);
#pragma unroll
        for (int ks = 0; ks < 2; ks++)
#pragma unroll
            for (int i = 0; i < 4; i++)
#pragma unroll
                for (int j = 0; j < 2; j++)
                    acc[i][j] = __builtin_amdgcn_mfma_f32_16x16x32_bf16(
                        a0[i][ks], bb[j][ks], acc[i][j], 0, 0, 0);
        __builtin_amdgcn_s_setprio(0);
        __builtin_amdgcn_s_barrier();

        // ---- phase 2: a1; stage B0(t+2) (B-halves freed at Ph1-end); Q01
#pragma unroll
        for (int i = 0; i < 4; i++) {
            a1[i][0] = *(const s16x8*)(Ap + 4096 + i * 1024 + aoff0);
            a1[i][1] = *(const s16x8*)(Ap + 4096 + i * 1024 + aoff1);
        }
        if (t + 2 < kTiles) STG_B(0, t + 2, p);
        __builtin_amdgcn_s_barrier();
        __builtin_amdgcn_s_setprio(1);
#pragma unroll
        for (int ks = 0; ks < 2; ks++)
#pragma unroll
            for (int i = 0; i < 4; i++)
#pragma unroll
                for (int j = 0; j < 2; j++)
                    acc[i][2 + j] = __builtin_amdgcn_mfma_f32_16x16x32_bf16(
                        a0[i][ks], bb[2 + j][ks], acc[i][2 + j], 0, 0, 0);
        __builtin_amdgcn_s_setprio(0);
        __builtin_amdgcn_s_barrier();

        // ---- phase 3: stage A0(t+2) (A-halves freed at Ph2-end); Q10
        if (t + 2 < kTiles) STG_A(0, t + 2, p);
        __builtin_amdgcn_s_barrier();
        __builtin_amdgcn_s_waitcnt(WAITCNT_LGKM0);
        __builtin_amdgcn_s_setprio(1);
#pragma unroll
        for (int ks = 0; ks < 2; ks++)
#pragma unroll
            for (int i = 0; i < 4; i++)
#pragma unroll
                for (int j = 0; j < 2; j++)
                    acc[4 + i][j] = __builtin_amdgcn_mfma_f32_16x16x32_bf16(
                        a1[i][ks], bb[j][ks], acc[4 + i][j], 0, 0, 0);
        __builtin_amdgcn_s_setprio(0);
        __builtin_amdgcn_s_barrier();

        // ---- phase 4: stage B1(t+2); Q11; counted vmcnt drains exactly tile t+1
        if (t + 2 < kTiles) STG_B(1, t + 2, p);
        __builtin_amdgcn_s_barrier();
        __builtin_amdgcn_s_setprio(1);
#pragma unroll
        for (int ks = 0; ks < 2; ks++)
#pragma unroll
            for (int i = 0; i < 4; i++)
#pragma unroll
                for (int j = 0; j < 2; j++)
                    acc[4 + i][2 + j] = __builtin_amdgcn_mfma_f32_16x16x32_bf16(
                        a1[i][ks], bb[2 + j][ks], acc[4 + i][2 + j], 0, 0, 0);
        __builtin_amdgcn_s_setprio(0);
        if (t + 2 < kTiles) __builtin_amdgcn_s_waitcnt(WAITCNT_VM6);
        else if (t + 1 < kTiles) __builtin_amdgcn_s_waitcnt(WAITCNT_VM0);
        __builtin_amdgcn_s_barrier();
    }
#undef STG_A
#undef STG_B

    // ---- epilogue: acc C/D layout col = lane&15, row = quad*4 + reg [m89/m91].
    // Stage into LDS (swizzle: 16B/32B group ^= ((row>>2)&3) == quad -> conflict-free
    // writes; full-row reads conflict-free), then fully-coalesced global stores.
    // All K-loop LDS reads retired (consumed by MFMA) before the loop's final barrier.
    const long long cb = (long long)bz * sC + (long long)kIdx * sK;
    if (OUT_BF16) {
        ushort* Cb = (ushort*)Cp;
        // stage: SH as [256 rows][16 groups of 16 ushorts], group ^= quad
#pragma unroll
        for (int j = 0; j < 4; j++) {
            const int cg = wn * 4 + j;  // col group (col>>4), uniform per wave
            const float bv = HAS_BIAS ? bias[tn * 256 + cg * 16 + l16] : 0.0f;
#pragma unroll
            for (int i = 0; i < 8; i++) {
                const int rbase = wm * 128 + i * 16 + quad * 4;
#pragma unroll
                for (int r = 0; r < 4; r++) {
                    const int row = rbase + r;
                    float v = acc[i][j][r] * scale + bv;
                    if (RELU) v = v > 0.f ? v : 0.f;
                    SH[row * 256 + ((cg ^ ((row >> 2) & 3)) << 4) + l16] = f2b(v);
                }
            }
        }
        __builtin_amdgcn_s_barrier();
        // readout: 16 passes x (16 rows x 32 chunks of 16B); 512B contiguous/row
        const int crow = tid >> 5;  // 0..15
        const int cch = tid & 31;   // 0..31
        const int g = cch >> 1, hh = cch & 1;
#pragma unroll
        for (int pass = 0; pass < 16; pass++) {
            const int row = pass * 16 + crow;
            s16x8 vv = *(const s16x8*)&SH[row * 256 + ((g ^ ((row >> 2) & 3)) << 4) + hh * 8];
            *(s16x8*)&Cb[cb + (long long)(tm * 256 + row) * ldc + tn * 256 + cch * 8] = vv;
        }
    } else {
        float* Cf = (float*)Cp;
        float* SHf = (float*)SH;  // [128 rows][32 groups of 8 floats] per half-pass
#pragma unroll
        for (int half = 0; half < 2; half++) {
            if (wm == half) {
#pragma unroll
                for (int j = 0; j < 4; j++) {
                    const int col = wn * 64 + j * 16 + l16;
                    const float bv = (HAS_BIAS && kIdx == 0) ? bias[tn * 256 + col] : 0.0f;
                    const int gg = col >> 3, cl = col & 7;
#pragma unroll
                    for (int i = 0; i < 8; i++) {
                        const int rbase = i * 16 + quad * 4;  // row within half
#pragma unroll
                        for (int r = 0; r < 4; r++) {
                            const int row = rbase + r;
                            float v = acc[i][j][r] * scale + bv;
                            if (RELU) v = v > 0.f ? v : 0.f;
                            SHf[row * 256 + ((gg ^ ((row >> 2) & 3)) << 3) + cl] = v;
                        }
                    }
                }
            }
            __builtin_amdgcn_s_barrier();
            // readout: 16 passes x (8 rows x 64 chunks of 16B); 1024B contiguous/row
            const int rr = tid >> 6, cc = tid & 63;
            const int g2 = cc >> 1, h2 = cc & 1;
#pragma unroll
            for (int pass = 0; pass < 16; pass++) {
                const int row = pass * 8 + rr;
                f32x4 vv = *(const f32x4*)&SHf[row * 256 + ((g2 ^ ((row >> 2) & 3)) << 3) + h2 * 4];
                *(f32x4*)&Cf[cb + (long long)(tm * 256 + half * 128 + row) * ldc + tn * 256 + cc * 4] = vv;
            }
            __builtin_amdgcn_s_barrier();
        }
    }
}

// ---------------- row softmax: bf16 [rows][2048] -> bf16, vectorized 8/thread -------

__global__ __launch_bounds__(256) void softmax_rows(const ushort* __restrict__ S,
                                                    ushort* __restrict__ P) {
    const int C = 2048;
    const long long row = blockIdx.x;
    const int tid = threadIdx.x;
    const ushort4* s4 = (const ushort4*)(S + row * C) + tid * 2;  // 8 contiguous elems
    ushort4 a = s4[0], bq = s4[1];
    float v[8];
    v[0] = b2f(a.x); v[1] = b2f(a.y); v[2] = b2f(a.z); v[3] = b2f(a.w);
    v[4] = b2f(bq.x); v[5] = b2f(bq.y); v[6] = b2f(bq.z); v[7] = b2f(bq.w);
    float mx = -1e30f;
#pragma unroll
    for (int i = 0; i < 8; i++) mx = fmaxf(mx, v[i]);
    __shared__ float red[256];
    red[tid] = mx;
    __syncthreads();
    for (int off = 128; off > 0; off >>= 1) {
        if (tid < off) red[tid] = fmaxf(red[tid], red[tid + off]);
        __syncthreads();
    }
    mx = red[0];
    __syncthreads();
    float sum = 0.f;
#pragma unroll
    for (int i = 0; i < 8; i++) {
        v[i] = __expf(v[i] - mx);
        sum += v[i];
    }
    red[tid] = sum;
    __syncthreads();
    for (int off = 128; off > 0; off >>= 1) {
        if (tid < off) red[tid] += red[tid + off];
        __syncthreads();
    }
    float inv = 1.f / red[0];
    ushort4 o0, o1;
    o0.x = f2b(v[0] * inv); o0.y = f2b(v[1] * inv); o0.z = f2b(v[2] * inv); o0.w = f2b(v[3] * inv);
    o1.x = f2b(v[4] * inv); o1.y = f2b(v[5] * inv); o1.z = f2b(v[6] * inv); o1.w = f2b(v[7] * inv);
    ushort4* p4 = (ushort4*)(P + row * C) + tid * 2;
    p4[0] = o0;
    p4[1] = o1;
}

// ---------------- fused residual(+partial-sum) + LayerNorm (D=1024) ----------------
// out = LN(X + Y + (Y2?)) ; Y2 nullable (split-K partial reduction fused here).

__global__ __launch_bounds__(256) void residual_ln(const float* __restrict__ X,
                                                   const float* __restrict__ Y,
                                                   const float* __restrict__ Y2,
                                                   const float* __restrict__ g,
                                                   const float* __restrict__ be,
                                                   float* __restrict__ outf,
                                                   ushort* __restrict__ outb) {
    const int D = 1024;
    const long long row = blockIdx.x;
    const float* x = X + row * D;
    const float* y = Y + row * D;
    const float* y2 = Y2 ? Y2 + row * D : nullptr;
    const int tid = threadIdx.x;
    float v[4];
    float s = 0.f, s2 = 0.f;
#pragma unroll
    for (int i = 0; i < 4; i++) {
        int c = tid + i * 256;
        float t = x[c] + y[c];
        if (y2) t += y2[c];
        v[i] = t;
        s += t;
        s2 += t * t;
    }
    __shared__ float r1[256], r2[256];
    r1[tid] = s;
    r2[tid] = s2;
    __syncthreads();
    for (int off = 128; off > 0; off >>= 1) {
        if (tid < off) {
            r1[tid] += r1[tid + off];
            r2[tid] += r2[tid + off];
        }
        __syncthreads();
    }
    float mu = r1[0] * (1.f / 1024.f);
    float var = r2[0] * (1.f / 1024.f) - mu * mu;
    float inv = rsqrtf(var + 1e-5f);
    float* of = outf + row * D;
    ushort* ob = outb ? outb + row * D : nullptr;
#pragma unroll
    for (int i = 0; i < 4; i++) {
        int c = tid + i * 256;
        float o = (v[i] - mu) * inv * g[c] + be[c];
        of[c] = o;
        if (ob) ob[c] = f2b(o);
    }
}

// ---------------- launch ----------------

extern "C" void kernel_launch(void* const* d_in, const int* in_sizes, int n_in,
                              void* d_out, int out_size, void* d_ws, size_t ws_size,
                              hipStream_t stream) {
    const float* x  = (const float*)d_in[0];
    const float* wq = (const float*)d_in[1];
    const float* bq = (const float*)d_in[2];
    const float* wk = (const float*)d_in[3];
    const float* bk = (const float*)d_in[4];
    const float* wv = (const float*)d_in[5];
    const float* bv = (const float*)d_in[6];
    const float* wo = (const float*)d_in[7];
    const float* bo = (const float*)d_in[8];
    const float* w1 = (const float*)d_in[9];
    const float* b1 = (const float*)d_in[10];
    const float* w2 = (const float*)d_in[11];
    const float* b2 = (const float*)d_in[12];
    const float* g1 = (const float*)d_in[13];
    const float* be1 = (const float*)d_in[14];
    const float* g2 = (const float*)d_in[15];
    const float* be2 = (const float*)d_in[16];
    float* out = (float*)d_out;
    char* ws = (char*)d_ws;

    const int Bz = 4, S = 2048, D = 1024, F = 4096;
    const int T = Bz * S;  // 8192 rows
    const size_t MBy = 1024ull * 1024ull;

    // workspace layout (byte offsets), lifetime-based reuse; peak 201 MB
    ushort* qkvT = (ushort*)(ws + 0);        // 6 MB  [3072][1024]; woT follows contiguously
    ushort* woT  = (ushort*)(ws + 6 * MBy);  // 2 MB
    ushort* w1T  = (ushort*)(ws + 8 * MBy);  // 8 MB   [F][D]
    ushort* w2T  = (ushort*)(ws + 16 * MBy); // 8 MB   [D][F]
    float*  bqkv = (float*)(ws + 24 * MBy);  // 12 KB  (dead after QKV gemm)
    ushort* xb   = (ushort*)(ws + 25 * MBy); // 16 MB  (dead after QKV gemm)
    ushort* qkv  = (ushort*)(ws + 41 * MBy); // 48 MB  [T][3072] (dead after scores+vT)
    ushort* vT   = (ushort*)(ws + 89 * MBy); // 16 MB  [B][D][S] (dead after ctx)
    ushort* scb  = (ushort*)(ws + 105 * MBy); // 32 MB bf16 scores (dead after softmax)
    ushort* attn = (ushort*)(ws + 169 * MBy); // 32 MB (dead after ctx)
    // reuse (non-overlapping lifetimes):
    float*  ctx0 = (float*)(ws + 105 * MBy); // 32 MB over scb (dead after add2_cast)
    float*  ctx1 = (float*)(ws + 137 * MBy); // 32 MB (dead after add2_cast)
    ushort* ctxb = (ushort*)(ws + 25 * MBy); // 16 MB over xb (dead after wo)
    float*  ao0 = (float*)(ws + 105 * MBy);  // 32 MB over ctx0 (dead after ln1)
    float*  ao1 = (float*)(ws + 137 * MBy);  // 32 MB (dead after ln1)
    float*  x1  = (float*)(ws + 41 * MBy);   // 32 MB over qkv (live to ln2)
    ushort* x1b = (ushort*)(ws + 73 * MBy);  // 16 MB over qkv (dead after ffn1)
    ushort* h   = (ushort*)(ws + 105 * MBy); // 64 MB over ao (after ln1)
    float*  ff0 = (float*)(ws + 169 * MBy);  // 32 MB over attn
    float*  ff1 = (float*)(ws + 73 * MBy);   // 32 MB over x1b+vT (both dead by ffn2)

    dim3 b32(32, 8);

    // 1) cast x -> bf16
    cast_f2b4<<<(T * D) / 1024, 256, 0, stream>>>(x, xb, (long long)(T * D) / 4);

    // 2) transpose-cast weights: wq/wk/wv/wo -> [qkvT|woT] in ONE dispatch; w1, w2
    transpose4_to_bf16<<<dim3(32, 32, 4), b32, 0, stream>>>(wq, wk, wv, wo, qkvT);
    transpose_to_bf16<float><<<dim3(128, 32, 1), b32, 0, stream>>>(w1, w1T, D, F, F, 0, 0);
    transpose_to_bf16<float><<<dim3(32, 128, 1), b32, 0, stream>>>(w2, w2T, F, D, D, 0, 0);

    // 3) fused bias vector [bq|bk|bv]
    concat3<<<12, 256, 0, stream>>>(bq, bk, bv, bqkv);

    // 4) fused QKV projection: [T][1024] x [3072][1024]^T -> [T][3072] bf16 (384 blocks)
    gemm256<1, 0, 1><<<dim3(3 * D / 256, T / 256, 1), 512, 0, stream>>>(
        xb, qkvT, qkv, bqkv, D, 1, 1.f, D, D, 3 * D, 0, 0, 0, 0);

    // 5) V^T per batch: qkv v-slice [S][1024] (ld 3072) -> [D][S]
    transpose_to_bf16<ushort><<<dim3(D / 32, S / 32, Bz), b32, 0, stream>>>(
        qkv + 2048, vT, S, D, 3 * D, (long long)S * 3 * D, (long long)S * D);

    // 6) scores = Q K^T / 32 -> bf16; A=q, B=k slices of qkv (ld 3072) (256 blocks)
    gemm256<1, 0, 0><<<dim3(S / 256, S / 256, Bz), 512, 0, stream>>>(
        qkv, qkv + 1024, scb, nullptr, D, 1, 0.03125f, 3 * D, 3 * D, S,
        (long long)S * 3 * D, (long long)S * 3 * D, (long long)S * S, 0);

    // 7) softmax rows -> bf16 attn
    softmax_rows<<<T, 256, 0, stream>>>(scb, attn);

    // 8) ctx partials = attn @ V (BT = V^T [D][S]), split-K=2 -> fp32 (256 blocks)
    gemm256<0, 0, 0><<<dim3(D / 256, S / 256, Bz * 2), 512, 0, stream>>>(
        attn, vT, ctx0, nullptr, S, 2, 1.f, S, S, D,
        (long long)S * S, (long long)D * S, (long long)S * D, (long long)(ctx1 - ctx0));

    // 8b) ctx = ctx0 + ctx1 -> bf16
    add2_cast<<<(T * D) / 1024, 256, 0, stream>>>(ctx0, ctx1, ctxb, (long long)(T * D) / 4);

    // 9) attn_out partials = ctx @ wo^T (+bo chunk 0), split-K=2 (256 blocks)
    gemm256<0, 0, 1><<<dim3(D / 256, T / 256, 2), 512, 0, stream>>>(
        ctxb, woT, ao0, bo, D, 2, 1.f, D, D, D, 0, 0, 0, (long long)(ao1 - ao0));

    // 10) x1 = LN(x + ao0 + ao1) -> fp32 + bf16 (split-K reduction fused)
    residual_ln<<<T, 256, 0, stream>>>(x, ao0, ao1, g1, be1, x1, x1b);

    // 11) h = relu(x1 @ w1 + b1) (bf16, 512 blocks)
    gemm256<1, 1, 1><<<dim3(F / 256, T / 256, 1), 512, 0, stream>>>(
        x1b, w1T, h, b1, D, 1, 1.f, D, D, F, 0, 0, 0, 0);

    // 12) ff partials = h @ w2 (+b2 on chunk 0), split-K=2 (256 blocks)
    gemm256<0, 0, 1><<<dim3(D / 256, T / 256, 2), 512, 0, stream>>>(
        h, w2T, ff0, b2, F, 2, 1.f, F, F, D, 0, 0, 0, (long long)(ff1 - ff0));

    // 13) out = LN(x1 + ff0 + ff1) -> d_out fp32 (split-K reduction fused)
    residual_ln<<<T, 256, 0, stream>>>(x1, ff0, ff1, g2, be2, out, nullptr);
}